// Round 6
// baseline (450.064 us; speedup 1.0000x reference)
//
#include <hip/hip_runtime.h>
#include <math.h>

#define BB 2
#define HH 8
#define SS 2048
#define CC 64
#define CIN 512
#define DDIM 512           // H*C
#define MM (BB*SS)         // 4096
#define NCHUNK (SS / 64)   // 32 key-chunks, full key domain per block

#define LOG2E 1.4426950408889634f
#define SHIFT2 (16.0f * LOG2E)   // softmax shift in log2 domain

using short8  = __attribute__((ext_vector_type(8))) short;
using float4v = __attribute__((ext_vector_type(4))) float;

__device__ __forceinline__ unsigned short tob(float f) {
    unsigned u = __float_as_uint(f);
    unsigned r = (u + 0x7fffu + ((u >> 16) & 1u)) >> 16;
    return (unsigned short)r;
}
__device__ __forceinline__ float fromb(unsigned short u) {
    return __uint_as_float(((unsigned)u) << 16);
}

// DMA global->LDS, 16 B per lane. Per-lane GLOBAL src address; LDS dest is
// wave-uniform base + lane*16 (m104/m173 semantics).
#define GLDS(srcp, ldsp)                                                     \
    __builtin_amdgcn_global_load_lds(                                        \
        (const __attribute__((address_space(1))) void*)(srcp),               \
        (__attribute__((address_space(3))) void*)(ldsp), 16, 0, 0)

// ---------------------------------------------------------------- convert ---
__global__ __launch_bounds__(256) void convert_all(
    const float* __restrict__ x,
    const float* __restrict__ wq, const float* __restrict__ wk,
    const float* __restrict__ wv, const float* __restrict__ wg,
    const float* __restrict__ wo,
    unsigned short* __restrict__ xb,
    unsigned short* __restrict__ wqb, unsigned short* __restrict__ wkb,
    unsigned short* __restrict__ wvb, unsigned short* __restrict__ wgb,
    unsigned short* __restrict__ wob)
{
    const int NX4 = MM * CIN / 4;       // 524288
    int i = blockIdx.x * blockDim.x + threadIdx.x;
    const float* src; unsigned short* dst; float scale = 1.0f; int off;
    if (i < NX4) { src = x; dst = xb; off = i; }
    else {
        int j = i - NX4;
        int seg = j >> 16;              // 65536 float4 per 512x512 weight
        off = j & 65535;
        // Wq pre-scaled by (1/8)*log2(e) so QK^T scores land in log2 units.
        if      (seg == 0) { src = wq; dst = wqb; scale = 0.125f * LOG2E; }
        else if (seg == 1) { src = wk; dst = wkb; }
        else if (seg == 2) { src = wv; dst = wvb; }
        else if (seg == 3) { src = wg; dst = wgb; }
        else               { src = wo; dst = wob; }
    }
    float4 v = ((const float4*)src)[off];
    ushort4 o;
    o.x = tob(v.x * scale); o.y = tob(v.y * scale);
    o.z = tob(v.z * scale); o.w = tob(v.w * scale);
    ((ushort4*)dst)[off] = o;
}

// ------------------------------------------------------------- projection ---
// mode (blockIdx.z): 0 Q->[B,H,S,C] (pre-scaled, log2-domain), 1 K->[B,H,S,C],
// 2 V->[B,H,C,S] (LDS transpose), 3 G=sigmoid(P+bg)->[MM][512]
__global__ __launch_bounds__(256) void proj_gemm(
    const unsigned short* __restrict__ X,
    const unsigned short* __restrict__ Wq,
    const unsigned short* __restrict__ Wk,
    const unsigned short* __restrict__ Wv,
    const unsigned short* __restrict__ Wg,
    const float* __restrict__ bg,
    unsigned short* __restrict__ Qd,
    unsigned short* __restrict__ Kd,
    unsigned short* __restrict__ Vd,
    unsigned short* __restrict__ Gd)
{
    __shared__ __align__(16) unsigned short At[64][72];
    __shared__ __align__(16) unsigned short Bt[64][72];

    int mode = blockIdx.z;
    const unsigned short* W = (mode == 0) ? Wq : (mode == 1) ? Wk : (mode == 2) ? Wv : Wg;

    int m0 = blockIdx.y * 64;
    int n0 = blockIdx.x * 64;
    int tid = threadIdx.x;
    int w = tid >> 6, lane = tid & 63;
    int quad = lane >> 4, l16 = lane & 15;
    int wm = w & 1, wn = w >> 1;

    float4v acc[2][2];
    for (int a = 0; a < 2; ++a) for (int c = 0; c < 2; ++c) acc[a][c] = (float4v)0.0f;

    for (int kc = 0; kc < CIN; kc += 64) {
        for (int it = 0; it < 2; ++it) {
            int idx = it * 2048 + tid * 8;
            int row = idx >> 6, col = idx & 63;
            *(short8*)&At[row][col] = *(const short8*)&X[(size_t)(m0 + row) * CIN + kc + col];
            *(short8*)&Bt[row][col] = *(const short8*)&W[(size_t)(n0 + row) * CIN + kc + col];
        }
        __syncthreads();
        for (int ks = 0; ks < 2; ++ks) {
            short8 a0 = *(const short8*)&At[wm * 32 + l16][ks * 32 + quad * 8];
            short8 a1 = *(const short8*)&At[wm * 32 + 16 + l16][ks * 32 + quad * 8];
            short8 b0 = *(const short8*)&Bt[wn * 32 + l16][ks * 32 + quad * 8];
            short8 b1 = *(const short8*)&Bt[wn * 32 + 16 + l16][ks * 32 + quad * 8];
            acc[0][0] = __builtin_amdgcn_mfma_f32_16x16x32_bf16(a0, b0, acc[0][0], 0, 0, 0);
            acc[0][1] = __builtin_amdgcn_mfma_f32_16x16x32_bf16(a0, b1, acc[0][1], 0, 0, 0);
            acc[1][0] = __builtin_amdgcn_mfma_f32_16x16x32_bf16(a1, b0, acc[1][0], 0, 0, 0);
            acc[1][1] = __builtin_amdgcn_mfma_f32_16x16x32_bf16(a1, b1, acc[1][1], 0, 0, 0);
        }
        __syncthreads();
    }

    if (mode == 2) {
        for (int a = 0; a < 2; ++a) for (int c = 0; c < 2; ++c)
            for (int r = 0; r < 4; ++r) {
                int ml = wm * 32 + a * 16 + quad * 4 + r;     // s-local
                int nl = wn * 32 + c * 16 + l16;              // c-local
                At[nl][ml] = tob(acc[a][c][r]);
            }
        __syncthreads();
        int bi = m0 >> 11, h = n0 >> 6, s0 = m0 & 2047;
        int crow = tid >> 2, seg = tid & 3;
        unsigned short* dp = Vd + (((size_t)(bi * HH + h) * CC) + crow) * SS + s0 + seg * 16;
        *(short8*)dp       = *(const short8*)&At[crow][seg * 16];
        *(short8*)(dp + 8) = *(const short8*)&At[crow][seg * 16 + 8];
        return;
    }

    for (int a = 0; a < 2; ++a) for (int c = 0; c < 2; ++c)
        for (int r = 0; r < 4; ++r) {
            int gm = m0 + wm * 32 + a * 16 + quad * 4 + r;
            int gn = n0 + wn * 32 + c * 16 + l16;
            float v = acc[a][c][r];
            if (mode <= 1) {
                int bi = gm >> 11, s = gm & 2047, h = gn >> 6, cc = gn & 63;
                unsigned short* d = (mode == 0) ? Qd : Kd;
                d[(((size_t)(bi * HH + h) * SS) + s) * CC + cc] = tob(v);
            } else {
                float g = 1.0f / (1.0f + __expf(-(v + bg[gn])));
                Gd[(size_t)gm * DDIM + gn] = tob(g);
            }
        }
}

// -------------------------------------------------------------- attention ---
// Full-domain flash attention, fixed-shift softmax (log2 domain):
//   O_row = ( sum_k 2^(qk*log2e + bias*log2e - SHIFT2) v ) / lsum * g
// Block = 64 q rows (4 waves x 16), 32 key-chunks, grid (32,16) = 512 blocks,
// 2 blocks/CU (LDS 73 KB).
// ROUND-6: staging via global_load_lds DMA + counted vmcnt + double-buffered
// LDS (the guide's T3/T4 pattern). Five rounds of register-held prefetch all
// failed the same way (compiler sinks/demotes the prefetch state; VGPR stuck
// at 72): DMA is issued where written — nothing to sink. vmcnt(8) keeps the
// next chunk's 8 DMAs in flight across both barriers; vmcnt never drains to
// 0 in the steady-state loop.
// K/V use pre-swizzled-SOURCE XOR (granule ^= row&7) so the linear LDS
// required by global_load_lds still gives uniform bank distribution on the
// ds_read_b128 fragments (equivalent to the old +72 padding).
__global__ __launch_bounds__(256, 2) void attn_kernel(
    const unsigned short* __restrict__ Q,
    const unsigned short* __restrict__ K,
    const unsigned short* __restrict__ V,
    const float* __restrict__ bias,
    const unsigned short* __restrict__ G,
    unsigned short* __restrict__ Om)   // [MM][DDIM] bf16 gated output
{
    __shared__ __align__(16) unsigned short Kt[2][64][64];   // [key][c], swz
    __shared__ __align__(16) unsigned short Vt[2][64][64];   // [c][key], swz
    __shared__ __align__(16) float Bs[2][64][64];            // [qrow][key]
    __shared__ __align__(16) unsigned short Pt[4][16][72];   // per-wave P

    int qb = blockIdx.x * 64;
    int bh = blockIdx.y;               // b*H + h
    int b = bh >> 3, h = bh & 7;
    int tid = threadIdx.x;
    int w = tid >> 6, lane = tid & 63;
    int quad = lane >> 4, l16 = lane & 15;
    int swl = l16 & 7;                 // read-side XOR key

    // per-block chunk-phase rotation (fixed-shift softmax is chunk-linear)
    int phase = (blockIdx.x + blockIdx.y) & (NCHUNK - 1);

    const unsigned short* Qbh = Q + (size_t)bh * SS * CC;
    const unsigned short* Kbh = K + (size_t)bh * SS * CC;
    const unsigned short* Vbh = V + (size_t)bh * CC * SS;
    const float* Bbh = bias + (size_t)bh * SS * SS;

    // Q fragments FIRST (they retire before the DMAs in vmcnt order)
    int qrow = qb + w * 16 + l16;
    short8 aq0 = *(const short8*)&Qbh[(size_t)qrow * CC + quad * 8];
    short8 aq1 = *(const short8*)&Qbh[(size_t)qrow * CC + 32 + quad * 8];

    float lsum[4] = {0.f, 0.f, 0.f, 0.f};
    float4v accO[4];
    for (int jn = 0; jn < 4; ++jn) accO[jn] = (float4v)0.0f;

    // DMA staging coords (wave-uniform LDS bases; per-lane global src)
    int row8  = lane >> 3;                       // 0..7
    int kswz  = (lane & 7) ^ row8;               // source-granule XOR swizzle
    int row16 = lane >> 4;                       // 0..3 (bias)
    int col16 = lane & 15;                       // bias 16B-granule in row

    // stage one 64-key chunk (8 DMAs/wave: 2 K, 2 V, 4 bias)
    auto STAGE = [&](int d, int kb) {
#pragma unroll
        for (int p = 0; p < 2; ++p) {
            int r0 = w * 16 + p * 8;
            GLDS(Kbh + (size_t)(kb + r0 + row8) * CC + kswz * 8, &Kt[d][r0][0]);
            GLDS(Vbh + (size_t)(r0 + row8) * SS + kb + kswz * 8, &Vt[d][r0][0]);
        }
#pragma unroll
        for (int t = 0; t < 4; ++t) {
            int r0 = w * 16 + t * 4;
            GLDS(Bbh + (size_t)(qb + r0 + row16) * SS + kb + col16 * 4, &Bs[d][r0][0]);
        }
    };

    // ---- prologue: stage chunks 0 and 1 (16 DMAs in flight)
    STAGE(0, phase * 64);
    STAGE(1, ((1 + phase) & (NCHUNK - 1)) * 64);

    for (int c = 0; c < NCHUNK; ++c) {
        int d = c & 1;
        // wait for chunk c's 8 DMAs (chunk c+1's 8 stay in flight);
        // final iteration: nothing behind, drain fully.
        if (c + 1 < NCHUNK) {
            asm volatile("s_waitcnt vmcnt(8)" ::: "memory");
        } else {
            asm volatile("s_waitcnt vmcnt(0)" ::: "memory");
        }
        __builtin_amdgcn_sched_barrier(0);
        __builtin_amdgcn_s_barrier();          // chunk c visible to all waves
        __builtin_amdgcn_sched_barrier(0);

        // ---- compute on buf d
        float4v sa[4];
#pragma unroll
        for (int j = 0; j < 4; ++j) sa[j] = (float4v)(-SHIFT2);
#pragma unroll
        for (int j = 0; j < 4; ++j) {
            short8 bk0 = *(const short8*)&Kt[d][j * 16 + l16][((quad    ) ^ swl) * 8];
            short8 bk1 = *(const short8*)&Kt[d][j * 16 + l16][((quad + 4) ^ swl) * 8];
            sa[j] = __builtin_amdgcn_mfma_f32_16x16x32_bf16(aq0, bk0, sa[j], 0, 0, 0);
            sa[j] = __builtin_amdgcn_mfma_f32_16x16x32_bf16(aq1, bk1, sa[j], 0, 0, 0);
        }

#pragma unroll
        for (int j = 0; j < 4; ++j)
#pragma unroll
            for (int r = 0; r < 4; ++r) {
                float bb = Bs[d][w * 16 + quad * 4 + r][j * 16 + l16];
                float p = __builtin_amdgcn_exp2f(fmaf(bb, LOG2E, sa[j][r]));
                lsum[r] += p;
                Pt[w][quad * 4 + r][j * 16 + l16] = tob(p);
            }

#pragma unroll
        for (int ks = 0; ks < 2; ++ks) {
            short8 ap = *(const short8*)&Pt[w][l16][ks * 32 + quad * 8];
#pragma unroll
            for (int jn = 0; jn < 4; ++jn) {
                short8 bv = *(const short8*)&Vt[d][jn * 16 + l16][((ks * 4 + quad) ^ swl) * 8];
                accO[jn] = __builtin_amdgcn_mfma_f32_16x16x32_bf16(ap, bv, accO[jn], 0, 0, 0);
            }
        }

        // all waves done READING buf d before restaging it
        __builtin_amdgcn_sched_barrier(0);
        asm volatile("s_waitcnt lgkmcnt(0)" ::: "memory");
        __builtin_amdgcn_s_barrier();
        __builtin_amdgcn_sched_barrier(0);

        if (c + 2 < NCHUNK)
            STAGE(d, ((c + 2 + phase) & (NCHUNK - 1)) * 64);
    }

    // row-sum reduce across 16 l16 lanes (keys are distributed over l16)
    float rl[4];
#pragma unroll
    for (int r = 0; r < 4; ++r) {
        float s = lsum[r];
        s += __shfl_xor(s, 1, 64);
        s += __shfl_xor(s, 2, 64);
        s += __shfl_xor(s, 4, 64);
        s += __shfl_xor(s, 8, 64);
        rl[r] = 1.0f / s;
    }

    // epilogue: O = accO/lsum * G  -> bf16 Om
    int mrow = b * SS + qb + w * 16 + quad * 4;          // +r
#pragma unroll
    for (int jn = 0; jn < 4; ++jn)
#pragma unroll
        for (int r = 0; r < 4; ++r) {
            int col = h * 64 + jn * 16 + l16;
            float g = fromb(G[(size_t)(mrow + r) * DDIM + col]);
            Om[(size_t)(mrow + r) * DDIM + col] = tob(accO[jn][r] * rl[r] * g);
        }
}

// ---------------------------------------------------------- output GEMM -----
__global__ __launch_bounds__(256) void out_gemm(
    const unsigned short* __restrict__ Og,
    const unsigned short* __restrict__ W,
    const float* __restrict__ bo,
    float* __restrict__ out)
{
    __shared__ __align__(16) unsigned short At[64][72];
    __shared__ __align__(16) unsigned short Bt[64][72];

    int m0 = blockIdx.y * 64;
    int n0 = blockIdx.x * 64;
    int tid = threadIdx.x;
    int w = tid >> 6, lane = tid & 63;
    int quad = lane >> 4, l16 = lane & 15;
    int wm = w & 1, wn = w >> 1;

    float4v acc[2][2];
    for (int a = 0; a < 2; ++a) for (int c = 0; c < 2; ++c) acc[a][c] = (float4v)0.0f;

    for (int kc = 0; kc < DDIM; kc += 64) {
        for (int it = 0; it < 2; ++it) {
            int idx = it * 2048 + tid * 8;
            int row = idx >> 6, col = idx & 63;
            *(short8*)&At[row][col] = *(const short8*)&Og[(size_t)(m0 + row) * DDIM + kc + col];
            *(short8*)&Bt[row][col] = *(const short8*)&W[(size_t)(n0 + row) * DDIM + kc + col];
        }
        __syncthreads();
        for (int ks = 0; ks < 2; ++ks) {
            short8 a0 = *(const short8*)&At[wm * 32 + l16][ks * 32 + quad * 8];
            short8 a1 = *(const short8*)&At[wm * 32 + 16 + l16][ks * 32 + quad * 8];
            short8 b0 = *(const short8*)&Bt[wn * 32 + l16][ks * 32 + quad * 8];
            short8 b1 = *(const short8*)&Bt[wn * 32 + 16 + l16][ks * 32 + quad * 8];
            acc[0][0] = __builtin_amdgcn_mfma_f32_16x16x32_bf16(a0, b0, acc[0][0], 0, 0, 0);
            acc[0][1] = __builtin_amdgcn_mfma_f32_16x16x32_bf16(a0, b1, acc[0][1], 0, 0, 0);
            acc[1][0] = __builtin_amdgcn_mfma_f32_16x16x32_bf16(a1, b0, acc[1][0], 0, 0, 0);
            acc[1][1] = __builtin_amdgcn_mfma_f32_16x16x32_bf16(a1, b1, acc[1][1], 0, 0, 0);
        }
        __syncthreads();
    }

    for (int a = 0; a < 2; ++a) for (int c = 0; c < 2; ++c)
        for (int r = 0; r < 4; ++r) {
            int gm = m0 + wm * 32 + a * 16 + quad * 4 + r;
            int gn = n0 + wn * 32 + c * 16 + l16;
            out[(size_t)gm * DDIM + gn] = acc[a][c][r] + bo[gn];
        }
}

// ------------------------------------------------------------------ launch --
extern "C" void kernel_launch(void* const* d_in, const int* in_sizes, int n_in,
                              void* d_out, int out_size, void* d_ws, size_t ws_size,
                              hipStream_t stream)
{
    const float* x    = (const float*)d_in[0];
    const float* bias = (const float*)d_in[1];
    const float* Wq   = (const float*)d_in[2];
    const float* Wk   = (const float*)d_in[3];
    const float* Wv   = (const float*)d_in[4];
    const float* Wo   = (const float*)d_in[5];
    const float* bo   = (const float*)d_in[6];
    const float* Wg   = (const float*)d_in[7];
    const float* bg   = (const float*)d_in[8];
    float* out = (float*)d_out;

    char* ws = (char*)d_ws;
    auto alloc = [&](size_t bytes) { char* p = ws; ws += (bytes + 255) & ~(size_t)255; return p; };
    unsigned short* xb  = (unsigned short*)alloc((size_t)MM * CIN * 2);
    unsigned short* wqb = (unsigned short*)alloc((size_t)DDIM * CIN * 2);
    unsigned short* wkb = (unsigned short*)alloc((size_t)DDIM * CIN * 2);
    unsigned short* wvb = (unsigned short*)alloc((size_t)DDIM * CIN * 2);
    unsigned short* wgb = (unsigned short*)alloc((size_t)DDIM * CIN * 2);
    unsigned short* wob = (unsigned short*)alloc((size_t)DDIM * CIN * 2);
    unsigned short* Qh  = (unsigned short*)alloc((size_t)BB * HH * SS * CC * 2);
    unsigned short* Kh  = (unsigned short*)alloc((size_t)BB * HH * SS * CC * 2);
    unsigned short* Vh  = (unsigned short*)alloc((size_t)BB * HH * SS * CC * 2);
    unsigned short* Gt  = (unsigned short*)alloc((size_t)MM * DDIM * 2);
    unsigned short* Om  = (unsigned short*)alloc((size_t)MM * DDIM * 2);

    convert_all<<<3328, 256, 0, stream>>>(x, Wq, Wk, Wv, Wg, Wo,
                                          xb, wqb, wkb, wvb, wgb, wob);
    proj_gemm<<<dim3(DDIM / 64, MM / 64, 4), 256, 0, stream>>>(
        xb, wqb, wkb, wvb, wgb, bg, Qh, Kh, Vh, Gt);
    attn_kernel<<<dim3(SS / 64, BB * HH), 256, 0, stream>>>(
        Qh, Kh, Vh, bias, Gt, Om);
    out_gemm<<<dim3(DDIM / 64, MM / 64), 256, 0, stream>>>(Om, wob, bo, out);
}